// Round 1
// baseline (441.080 us; speedup 1.0000x reference)
//
#include <hip/hip_runtime.h>
#include <cstdint>
#include <cstddef>

namespace {
constexpr int B = 128, N = 2048, A = 16, M = 64, D = 16;
constexpr int NCHUNK = 16;             // k1 split-K chunks
constexpr int CHUNK = N / NCHUNK;      // 128 n per chunk
constexpr size_t PART_ELEMS = (size_t)NCHUNK * B * M * D;  // 2,097,152
constexpr size_t VSQ_ELEMS  = (size_t)B * M * D;           // 131,072
constexpr size_t QKT_ELEMS  = (size_t)B * N * M;           // 16,777,216
}

// ---------------------------------------------------------------------------
// k1: partial v_raw[b,m,d] per (m, K-chunk).  part[chunk][b][m][d]
// block = (m, chunk), 256 threads, thread = (dp, bq) -> 4 b x 2 d outputs
// ---------------------------------------------------------------------------
__global__ __launch_bounds__(256) void k1_partial(const float* __restrict__ in,
                                                  const float* __restrict__ w,
                                                  float* __restrict__ part) {
    const int m     = blockIdx.x;
    const int chunk = blockIdx.y;
    const int t     = threadIdx.x;
    // pad 20 (16B-aligned rows, b-stride-1 lane reads -> conflict-free)
    __shared__ __align__(16) float in_tile[4][B][20];
    __shared__ __align__(16) float w_t[4][D][20];   // [nn][d][a] transposed
    const int dp = t & 7;
    const int d0 = dp * 2;
    const int bq = t >> 3;                           // 0..31
    float acc[4][2] = {};
    const int nbase = chunk * CHUNK;
    for (int g = 0; g < CHUNK / 4; ++g) {
        const int n0 = nbase + g * 4;
        // input: 4n x 128b x 16a = 2048 float4, 8/thread, coalesced (per-b 256B)
        #pragma unroll
        for (int j = 0; j < 8; ++j) {
            const int c = j * 256 + t;
            const int b = c >> 4;
            const int r = c & 15;                    // r = nn*4 + a4
            const float4 x = *reinterpret_cast<const float4*>(
                in + (size_t)b * (N * A) + (size_t)n0 * A + r * 4);
            const int nn = r >> 2, a4 = r & 3;
            *reinterpret_cast<float4*>(&in_tile[nn][b][a4 * 4]) = x;
        }
        // w: 4n x 16a x 16d (this m) = 256 float4, 1/thread, store transposed
        {
            const int c = t;
            const int nn = c >> 6;
            const int r  = c & 63;
            const int a = r >> 2, d4 = r & 3;
            const float4 x = *reinterpret_cast<const float4*>(
                w + ((((size_t)(n0 + nn)) * A + a) * M + m) * D + d4 * 4);
            w_t[nn][d4 * 4 + 0][a] = x.x;
            w_t[nn][d4 * 4 + 1][a] = x.y;
            w_t[nn][d4 * 4 + 2][a] = x.z;
            w_t[nn][d4 * 4 + 3][a] = x.w;
        }
        __syncthreads();
        #pragma unroll
        for (int nn = 0; nn < 4; ++nn) {
            #pragma unroll
            for (int a4 = 0; a4 < 4; ++a4) {
                const int a0 = a4 * 4;
                const float4 w40 = *reinterpret_cast<const float4*>(&w_t[nn][d0][a0]);
                const float4 w41 = *reinterpret_cast<const float4*>(&w_t[nn][d0 + 1][a0]);
                #pragma unroll
                for (int i = 0; i < 4; ++i) {
                    const int b = bq + 32 * i;       // stride-1 lanes -> no conflicts
                    const float4 x = *reinterpret_cast<const float4*>(&in_tile[nn][b][a0]);
                    acc[i][0] += x.x * w40.x + x.y * w40.y + x.z * w40.z + x.w * w40.w;
                    acc[i][1] += x.x * w41.x + x.y * w41.y + x.z * w41.z + x.w * w41.w;
                }
            }
        }
        __syncthreads();
    }
    #pragma unroll
    for (int i = 0; i < 4; ++i) {
        const int b = bq + 32 * i;
        const size_t o = (size_t)chunk * (B * M * D) + ((size_t)b * M + m) * D;
        part[o + d0]     = acc[i][0];
        part[o + d0 + 1] = acc[i][1];
    }
}

// ---------------------------------------------------------------------------
// k2: reduce partials -> v_raw -> squash -> v_sq (ws) ; LayerNorm -> out_v
// one thread per (b,m,d); width-16 shuffle reductions over d
// ---------------------------------------------------------------------------
__global__ __launch_bounds__(256) void k2_squash_ln(const float* __restrict__ part,
                                                    const float* __restrict__ gamma,
                                                    const float* __restrict__ beta,
                                                    float* __restrict__ v_sq,
                                                    float* __restrict__ out_v) {
    const int idx = blockIdx.x * 256 + threadIdx.x;  // 0..131071
    const int d   = idx & 15;
    float s = 0.f;
    #pragma unroll
    for (int c = 0; c < NCHUNK; ++c) s += part[(size_t)c * (B * M * D) + idx];
    const float v = s * (1.0f / 64.0f);              // uniform routing qk = 1/m
    float sq = v * v;
    #pragma unroll
    for (int off = 1; off < 16; off <<= 1) sq += __shfl_xor(sq, off, 16);
    const float f  = sqrtf(sq) / (1.0f + sq);        // squash factor
    const float vs = v * f;
    v_sq[idx] = vs;
    float mu = vs;
    #pragma unroll
    for (int off = 1; off < 16; off <<= 1) mu += __shfl_xor(mu, off, 16);
    mu *= (1.0f / 16.0f);
    const float dd = vs - mu;
    float var = dd * dd;
    #pragma unroll
    for (int off = 1; off < 16; off <<= 1) var += __shfl_xor(var, off, 16);
    var *= (1.0f / 16.0f);
    out_v[idx] = dd / sqrtf(var + 1e-5f) * gamma[d] + beta[d];
}

// ---------------------------------------------------------------------------
// k3: new_qk[b,n,m] = sum_a in[b,n,a] * (sum_d w[n,a,m,d]*v_sq[b,m,d])
// block = (m-quad, 32-n chunk), 256 threads; thread = (nl, mq, bp) owning
// 2 b x 2 m outputs per n; v_sq rows live in registers (16 float4).
// DIRECT=0: write ws qk_t[m][b][n] (contiguous; transposed later)
// DIRECT=1: write out[b][n][m] directly (fallback if ws too small)
// ---------------------------------------------------------------------------
template<int DIRECT>
__global__ __launch_bounds__(256) void k3_qk(const float* __restrict__ in,
                                             const float* __restrict__ w,
                                             const float* __restrict__ v_sq,
                                             float* __restrict__ dst) {
    const int m0 = blockIdx.x * 4;
    const int nc = blockIdx.y;                       // 0..63, 32 n each
    const int t  = threadIdx.x;
    const int nl = t >> 7;                           // wave-uniform
    const int mq = (t >> 6) & 1;                     // wave-uniform
    const int bp = t & 63;
    __shared__ __align__(16) float in_tile[2][B][17];
    __shared__ __align__(16) float w_tile[2][A][4][D];  // [nl][a][mloc][d]
    float4 v[2][2][4];                               // [bi][mj][k] : 64 VGPRs
    #pragma unroll
    for (int bi = 0; bi < 2; ++bi)
        #pragma unroll
        for (int mj = 0; mj < 2; ++mj) {
            const int b = bp + bi * 64;
            const int m = m0 + mq * 2 + mj;
            #pragma unroll
            for (int k = 0; k < 4; ++k)
                v[bi][mj][k] = *reinterpret_cast<const float4*>(
                    v_sq + ((size_t)b * M + m) * D + k * 4);
        }
    const int nbase = nc * 32;
    for (int g = 0; g < 16; ++g) {
        const int n0 = nbase + g * 2;
        // input: 2n x 128b x 16a = 1024 float4, 4/thread
        #pragma unroll
        for (int j = 0; j < 4; ++j) {
            const int c = j * 256 + t;
            const int b = c >> 3;
            const int r = c & 7;                     // nn*4 + a4
            const float4 x = *reinterpret_cast<const float4*>(
                in + (size_t)b * (N * A) + (size_t)n0 * A + r * 4);
            const int nn = r >> 2, a4 = r & 3;
            in_tile[nn][b][a4 * 4 + 0] = x.x;        // pad-17 rows -> scalar stores
            in_tile[nn][b][a4 * 4 + 1] = x.y;
            in_tile[nn][b][a4 * 4 + 2] = x.z;
            in_tile[nn][b][a4 * 4 + 3] = x.w;
        }
        // w: 2n x 16a x 4m x 16d = 512 float4, 2/thread, coalesced (256B/(n,a))
        #pragma unroll
        for (int j = 0; j < 2; ++j) {
            const int c = j * 256 + t;
            const int nn = c >> 8;
            const int r  = c & 255;
            const int a = r >> 4;
            const int mloc = (r >> 2) & 3;
            const int d4 = r & 3;
            const float4 x = *reinterpret_cast<const float4*>(
                w + ((((size_t)(n0 + nn)) * A + a) * M + (m0 + mloc)) * D + d4 * 4);
            *reinterpret_cast<float4*>(&w_tile[nn][a][mloc][d4 * 4]) = x;
        }
        __syncthreads();
        float qk[2][2] = {};
        #pragma unroll
        for (int a = 0; a < A; ++a) {
            const float x0 = in_tile[nl][bp][a];
            const float x1 = in_tile[nl][bp + 64][a];
            #pragma unroll
            for (int mj = 0; mj < 2; ++mj) {
                float g0 = 0.f, g1 = 0.f;
                #pragma unroll
                for (int k = 0; k < 4; ++k) {
                    const float4 wv = *reinterpret_cast<const float4*>(
                        &w_tile[nl][a][mq * 2 + mj][k * 4]);  // wave-uniform bcast
                    g0 += wv.x * v[0][mj][k].x + wv.y * v[0][mj][k].y
                        + wv.z * v[0][mj][k].z + wv.w * v[0][mj][k].w;
                    g1 += wv.x * v[1][mj][k].x + wv.y * v[1][mj][k].y
                        + wv.z * v[1][mj][k].z + wv.w * v[1][mj][k].w;
                }
                qk[0][mj] += x0 * g0;
                qk[1][mj] += x1 * g1;
            }
        }
        const int n = n0 + nl;
        #pragma unroll
        for (int bi = 0; bi < 2; ++bi)
            #pragma unroll
            for (int mj = 0; mj < 2; ++mj) {
                const int b = bp + bi * 64;
                const int m = m0 + mq * 2 + mj;
                if (DIRECT)
                    dst[((size_t)b * N + n) * M + m] = qk[bi][mj];
                else
                    dst[(size_t)m * (B * N) + (size_t)b * N + n] = qk[bi][mj];
            }
        __syncthreads();
    }
}

// ---------------------------------------------------------------------------
// k4: transpose qk_t[m][b][n] -> out[b][n][m], 64x64 LDS tiles per b
// ---------------------------------------------------------------------------
__global__ __launch_bounds__(256) void k4_transpose(const float* __restrict__ src,
                                                    float* __restrict__ dst) {
    const int ntile = blockIdx.x;                    // 0..31 (64 n each)
    const int b     = blockIdx.y;
    const int t     = threadIdx.x;
    __shared__ float tile[64][65];
    #pragma unroll
    for (int j = 0; j < 4; ++j) {
        const int c  = j * 256 + t;
        const int mm = c >> 4;
        const int n4 = c & 15;
        const float4 x = *reinterpret_cast<const float4*>(
            src + (size_t)mm * (B * N) + (size_t)b * N + ntile * 64 + n4 * 4);
        tile[mm][n4 * 4 + 0] = x.x;
        tile[mm][n4 * 4 + 1] = x.y;
        tile[mm][n4 * 4 + 2] = x.z;
        tile[mm][n4 * 4 + 3] = x.w;
    }
    __syncthreads();
    #pragma unroll
    for (int j = 0; j < 4; ++j) {
        const int c  = j * 256 + t;
        const int nn = c >> 4;
        const int m4 = c & 15;
        float4 y;
        y.x = tile[m4 * 4 + 0][nn];
        y.y = tile[m4 * 4 + 1][nn];
        y.z = tile[m4 * 4 + 2][nn];
        y.w = tile[m4 * 4 + 3][nn];
        *reinterpret_cast<float4*>(
            dst + ((size_t)b * N + ntile * 64 + nn) * M + m4 * 4) = y;
    }
}

// ---------------------------------------------------------------------------
extern "C" void kernel_launch(void* const* d_in, const int* in_sizes, int n_in,
                              void* d_out, int out_size, void* d_ws, size_t ws_size,
                              hipStream_t stream) {
    const float* in    = (const float*)d_in[0];
    const float* w     = (const float*)d_in[1];
    const float* gamma = (const float*)d_in[2];
    const float* beta  = (const float*)d_in[3];
    float* out_qk = (float*)d_out;
    float* out_v  = out_qk + (size_t)B * N * M;      // outputs concatenated
    float* part = (float*)d_ws;
    float* v_sq = part + PART_ELEMS;
    float* qk_t = v_sq + VSQ_ELEMS;
    const bool big_ws =
        ws_size >= (PART_ELEMS + VSQ_ELEMS + QKT_ELEMS) * sizeof(float);

    k1_partial<<<dim3(M, NCHUNK), 256, 0, stream>>>(in, w, part);
    k2_squash_ln<<<dim3((B * M * D) / 256), 256, 0, stream>>>(part, gamma, beta,
                                                              v_sq, out_v);
    if (big_ws) {
        k3_qk<0><<<dim3(M / 4, 64), 256, 0, stream>>>(in, w, v_sq, qk_t);
        k4_transpose<<<dim3(N / 64, B), 256, 0, stream>>>(qk_t, out_qk);
    } else {
        k3_qk<1><<<dim3(M / 4, 64), 256, 0, stream>>>(in, w, v_sq, out_qk);
    }
}

// Round 2
// 125.925 us; speedup vs baseline: 3.5027x; 3.5027x over previous
//
#include <hip/hip_runtime.h>
#include <cstdint>
#include <cstddef>

typedef short bfrag __attribute__((ext_vector_type(8)));   // 8 bf16 (4 VGPR)
typedef float facc  __attribute__((ext_vector_type(4)));   // 4 f32 acc

namespace {
constexpr int B = 128, N = 2048, A = 16, M = 64, D = 16;
constexpr int NA = N * A;            // 32768 (GEMM K)
constexpr int MD = M * D;            // 1024  (GEMM N)
constexpr size_t C_ELEMS = (size_t)B * MD;  // 131072
}

static __device__ __forceinline__ ushort f2bf(float x) {  // RNE f32->bf16
    uint u = __float_as_uint(x);
    u += 0x7fffu + ((u >> 16) & 1u);
    return (ushort)(u >> 16);
}
static __device__ __forceinline__ bfrag ld_frag16(const ushort* p) {  // 16B-aligned
    union { uint4 q; bfrag v; } u;
    u.q = *(const uint4*)p;
    return u.v;
}
static __device__ __forceinline__ bfrag ld_frag4(const ushort* p) {   // 4B-aligned
    const uint* q = (const uint*)p;
    union { uint a[4]; bfrag v; } u;
    u.a[0] = q[0]; u.a[1] = q[1]; u.a[2] = q[2]; u.a[3] = q[3];
    return u.v;
}

// ---------------------------------------------------------------------------
// k1: split-K bf16 MFMA GEMM. part[chunk][b][md] = sum_{na in chunk} in*w
// grid (4 md-groups of 256, nch chunks), 512 thr = 8 waves (2 b-halves x 4 md-quads)
// wave tile 64b x 64md = 4x4 fragment tiles; KT=64 staged per iter, reg-prefetch.
// ---------------------------------------------------------------------------
__global__ __launch_bounds__(512, 2) void k1_mfma(const float* __restrict__ in,
                                                  const float* __restrict__ w,
                                                  float* __restrict__ part,
                                                  int nch) {
    const int mdg   = blockIdx.x;              // md0 = 256*mdg
    const int chunk = blockIdx.y;
    const int t     = threadIdx.x;
    const int nap   = NA / nch;                // na per chunk
    const int nkt   = nap / 64;
    __shared__ __align__(16) ushort in_t[128 * 72];  // [b][k] rows 144B (16B-aligned)
    __shared__ __align__(16) ushort w_t[256 * 66];   // [md][k] rows 132B (4B-aligned reads)
    const int wv = t >> 6, tl = t & 63;
    const int wb = wv >> 2, wm = wv & 3;       // wave: b-half, md-quarter
    const int lr = tl & 15, hi = tl >> 4;

    facc acc[4][4];
    #pragma unroll
    for (int i = 0; i < 4; ++i)
        #pragma unroll
        for (int j = 0; j < 4; ++j) acc[i][j] = facc{0.f, 0.f, 0.f, 0.f};

    float4 pin[4], pw[8];
    const int ib  = t >> 4, ik = t & 15;       // in-stage: +q*32 b rows
    const int wk  = t >> 6, wmd = t & 63;      // w-stage: +q*8 k rows

    int na0 = (size_t)chunk * nap;
    // prologue loads (KT 0)
    #pragma unroll
    for (int q = 0; q < 4; ++q)
        pin[q] = *(const float4*)(in + (size_t)(q * 32 + ib) * NA + na0 + ik * 4);
    #pragma unroll
    for (int q = 0; q < 8; ++q)
        pw[q] = *(const float4*)(w + (size_t)(na0 + q * 8 + wk) * MD + mdg * 256 + wmd * 4);

    for (int kt = 0; kt < nkt; ++kt) {
        __syncthreads();                       // prev compute done reading LDS
        // stage regs -> LDS (bf16), w transposed
        #pragma unroll
        for (int q = 0; q < 4; ++q) {
            union { ushort s[4]; uint2 u; } pk;
            pk.s[0] = f2bf(pin[q].x); pk.s[1] = f2bf(pin[q].y);
            pk.s[2] = f2bf(pin[q].z); pk.s[3] = f2bf(pin[q].w);
            *(uint2*)(&in_t[(q * 32 + ib) * 72 + ik * 4]) = pk.u;
        }
        #pragma unroll
        for (int q = 0; q < 8; ++q) {
            const int krow = q * 8 + wk;
            w_t[(wmd * 4 + 0) * 66 + krow] = f2bf(pw[q].x);
            w_t[(wmd * 4 + 1) * 66 + krow] = f2bf(pw[q].y);
            w_t[(wmd * 4 + 2) * 66 + krow] = f2bf(pw[q].z);
            w_t[(wmd * 4 + 3) * 66 + krow] = f2bf(pw[q].w);
        }
        __syncthreads();
        if (kt + 1 < nkt) {                    // prefetch next KT (overlaps MFMA)
            const int nan = na0 + 64;
            #pragma unroll
            for (int q = 0; q < 4; ++q)
                pin[q] = *(const float4*)(in + (size_t)(q * 32 + ib) * NA + nan + ik * 4);
            #pragma unroll
            for (int q = 0; q < 8; ++q)
                pw[q] = *(const float4*)(w + (size_t)(nan + q * 8 + wk) * MD + mdg * 256 + wmd * 4);
        }
        // compute KT: 2 k-steps (K=32) x 16 MFMA
        #pragma unroll
        for (int ks = 0; ks < 2; ++ks) {
            bfrag af[4], bf[4];
            #pragma unroll
            for (int bt = 0; bt < 4; ++bt)
                af[bt] = ld_frag16(&in_t[(wb * 64 + bt * 16 + lr) * 72 + ks * 32 + hi * 8]);
            #pragma unroll
            for (int mt = 0; mt < 4; ++mt)
                bf[mt] = ld_frag4(&w_t[(wm * 64 + mt * 16 + lr) * 66 + ks * 32 + hi * 8]);
            #pragma unroll
            for (int bt = 0; bt < 4; ++bt)
                #pragma unroll
                for (int mt = 0; mt < 4; ++mt)
                    acc[bt][mt] = __builtin_amdgcn_mfma_f32_16x16x32_bf16(
                        af[bt], bf[mt], acc[bt][mt], 0, 0, 0);
        }
        na0 += 64;
    }
    // store partials: C row = 4*hi + r (b), col = lane&15 (md)  [verified layout]
    #pragma unroll
    for (int bt = 0; bt < 4; ++bt)
        #pragma unroll
        for (int mt = 0; mt < 4; ++mt) {
            const int b  = wb * 64 + bt * 16 + hi * 4;
            const int md = mdg * 256 + wm * 64 + mt * 16 + lr;
            #pragma unroll
            for (int r = 0; r < 4; ++r)
                part[((size_t)chunk * B + b + r) * MD + md] = acc[bt][mt][r];
        }
}

// ---------------------------------------------------------------------------
// k2: reduce partials -> v_raw -> squash -> v_sq (ws); LayerNorm -> out_v
// ---------------------------------------------------------------------------
__global__ __launch_bounds__(256) void k2_squash_ln(const float* __restrict__ part,
                                                    const float* __restrict__ gamma,
                                                    const float* __restrict__ beta,
                                                    float* __restrict__ v_sq,
                                                    float* __restrict__ out_v,
                                                    int nch) {
    const int idx = blockIdx.x * 256 + threadIdx.x;   // (b*64+m)*16+d
    const int d   = idx & 15;
    float s = 0.f;
    for (int c = 0; c < nch; ++c) s += part[(size_t)c * C_ELEMS + idx];
    const float v = s * (1.0f / 64.0f);               // uniform routing 1/m
    float sq = v * v;
    #pragma unroll
    for (int off = 1; off < 16; off <<= 1) sq += __shfl_xor(sq, off, 16);
    const float f  = sqrtf(sq) / (1.0f + sq);         // squash factor
    const float vs = v * f;
    v_sq[idx] = vs;
    float mu = vs;
    #pragma unroll
    for (int off = 1; off < 16; off <<= 1) mu += __shfl_xor(mu, off, 16);
    mu *= (1.0f / 16.0f);
    const float dd = vs - mu;
    float var = dd * dd;
    #pragma unroll
    for (int off = 1; off < 16; off <<= 1) var += __shfl_xor(var, off, 16);
    var *= (1.0f / 16.0f);
    out_v[idx] = dd / sqrtf(var + 1e-5f) * gamma[d] + beta[d];
}

// ---------------------------------------------------------------------------
// k3: qk[b,n,m] = sum_d (sum_a in[b,n,a] w[n,a,m,d]) * v_sq[b,m,d]
// Per n: MFMA A=w^T (rows=d, K=a zero-padded to 32), B=in^T (cols=b).
// C row = 4*hi+r = d, col = lane&15 = b -> 4 FMA vs reg-resident v_sq,
// shfl_xor(16,32) completes d-sum; float4 coalesced qk writes.
// grid (4 m-groups of 16, 128 n-segments of 16), 512 thr = 8 waves (b-tiles).
// ---------------------------------------------------------------------------
__global__ __launch_bounds__(512, 2) void k3_mfma(const float* __restrict__ in,
                                                  const float* __restrict__ w,
                                                  const float* __restrict__ vsq,
                                                  float* __restrict__ qk) {
    const int mg = blockIdx.x, seg = blockIdx.y;
    const int m0 = mg * 16, n0 = seg * 16;
    const int t  = threadIdx.x;
    const int wv = t >> 6, tl = t & 63;
    const int lr = tl & 15, hi = tl >> 4;
    const int bb = wv * 16 + lr;                      // this lane's b
    __shared__ __align__(16) ushort wt3[2][16 * 392]; // [m][d][a]: m*392+d*24+a
    __shared__ __align__(16) ushort inb[2][128 * 24]; // [b][a]: b*24+a

    float vsr[16][4];                                 // v_sq[bb][m0+mi][4hi+r]
    #pragma unroll
    for (int mi = 0; mi < 16; ++mi) {
        const float4 v = *(const float4*)(vsq + ((size_t)bb * M + m0 + mi) * D + hi * 4);
        vsr[mi][0] = v.x; vsr[mi][1] = v.y; vsr[mi][2] = v.z; vsr[mi][3] = v.w;
    }
    const int sa = t >> 6, smd = t & 63;              // w-stage coords
    const int mloc = smd >> 2, d0 = (smd & 3) * 4;
    const int sb = t >> 2, saf = t & 3;               // in-stage coords
    float4 pw0, pw1, pinr;
    const int koff = (hi < 2) ? hi * 8 : 0;           // clamp addr; frags zeroed hi>=2

    auto ldg = [&](int n) {
        pw0  = *(const float4*)(w + (size_t)(n * 16 + sa) * MD + m0 * 16 + smd * 4);
        pw1  = *(const float4*)(w + (size_t)(n * 16 + sa + 8) * MD + m0 * 16 + smd * 4);
        pinr = *(const float4*)(in + (size_t)sb * NA + n * 16 + saf * 4);
    };
    auto stg = [&](int p) {
        ushort* wb_ = &wt3[p][mloc * 392];
        wb_[(d0 + 0) * 24 + sa] = f2bf(pw0.x);
        wb_[(d0 + 1) * 24 + sa] = f2bf(pw0.y);
        wb_[(d0 + 2) * 24 + sa] = f2bf(pw0.z);
        wb_[(d0 + 3) * 24 + sa] = f2bf(pw0.w);
        wb_[(d0 + 0) * 24 + sa + 8] = f2bf(pw1.x);
        wb_[(d0 + 1) * 24 + sa + 8] = f2bf(pw1.y);
        wb_[(d0 + 2) * 24 + sa + 8] = f2bf(pw1.z);
        wb_[(d0 + 3) * 24 + sa + 8] = f2bf(pw1.w);
        union { ushort s[4]; uint2 u; } pk;
        pk.s[0] = f2bf(pinr.x); pk.s[1] = f2bf(pinr.y);
        pk.s[2] = f2bf(pinr.z); pk.s[3] = f2bf(pinr.w);
        *(uint2*)(&inb[p][sb * 24 + saf * 4]) = pk.u;
    };

    ldg(n0);
    stg(0);
    __syncthreads();
    for (int i = 0; i < 16; ++i) {
        const int n = n0 + i, p = i & 1;
        if (i + 1 < 16) ldg(n0 + i + 1);              // overlap with compute
        // B-frag (in^T), zero upper-K lanes (avoid 0*NaN from LDS garbage)
        uint4 braw = *(const uint4*)(&inb[p][bb * 24 + koff]);
        if (hi >= 2) { braw.x = 0u; braw.y = 0u; braw.z = 0u; braw.w = 0u; }
        union { uint4 q; bfrag v; } bu; bu.q = braw;
        const bfrag binf = bu.v;
        float qk_[4];
        const facc zero = facc{0.f, 0.f, 0.f, 0.f};
        #pragma unroll
        for (int mi = 0; mi < 16; ++mi) {
            uint4 araw = *(const uint4*)(&wt3[p][mi * 392 + lr * 24 + koff]);
            if (hi >= 2) { araw.x = 0u; araw.y = 0u; araw.z = 0u; araw.w = 0u; }
            union { uint4 q; bfrag v; } au; au.q = araw;
            const facc c = __builtin_amdgcn_mfma_f32_16x16x32_bf16(au.v, binf, zero, 0, 0, 0);
            float r0 = c[0] * vsr[mi][0] + c[1] * vsr[mi][1]
                     + c[2] * vsr[mi][2] + c[3] * vsr[mi][3];
            r0 += __shfl_xor(r0, 16);
            r0 += __shfl_xor(r0, 32);
            qk_[mi & 3] = (hi == (mi >> 2)) ? r0 : qk_[mi & 3];
        }
        const float4 o = {qk_[0], qk_[1], qk_[2], qk_[3]};
        *(float4*)(qk + ((size_t)bb * N + n) * M + m0 + hi * 4) = o;
        __syncthreads();
        if (i + 1 < 16) { stg((i + 1) & 1); __syncthreads(); }
    }
}

// ---------------------------------------------------------------------------
extern "C" void kernel_launch(void* const* d_in, const int* in_sizes, int n_in,
                              void* d_out, int out_size, void* d_ws, size_t ws_size,
                              hipStream_t stream) {
    const float* in    = (const float*)d_in[0];
    const float* w     = (const float*)d_in[1];
    const float* gamma = (const float*)d_in[2];
    const float* beta  = (const float*)d_in[3];
    float* out_qk = (float*)d_out;
    float* out_v  = out_qk + (size_t)B * N * M;

    int nch = 64;
    if (ws_size < (64 + 1) * C_ELEMS * sizeof(float)) nch = 16;
    if (ws_size < (16 + 1) * C_ELEMS * sizeof(float)) nch = 8;
    float* part = (float*)d_ws;
    float* vsq  = part + (size_t)nch * C_ELEMS;

    k1_mfma<<<dim3(4, nch), 512, 0, stream>>>(in, w, part, nch);
    k2_squash_ln<<<(int)(C_ELEMS / 256), 256, 0, stream>>>(part, gamma, beta, vsq, out_v, nch);
    k3_mfma<<<dim3(4, 128), 512, 0, stream>>>(in, w, vsq, out_qk);
}